// Round 16
// baseline (119.750 us; speedup 1.0000x reference)
//
#include <hip/hip_runtime.h>

#define NROWS 2048
#define MCOLS 2048

// ---- d_ws layout (float offsets); rows padded to stride 20 ----
// sum-form tables (champion) + exp-form tables (experiment)
#define OFF_AF 0
#define OFF_AS (OFF_AF + NROWS * 20)
#define OFF_BF (OFF_AS + NROWS * 20)
#define OFF_BS (OFF_BF + NROWS * 20)
#define OFF_TAF (OFF_BS + NROWS * 20)
#define OFF_TAS (OFF_TAF + NROWS * 20)
#define OFF_TBF (OFF_TAS + NROWS * 20)
#define OFF_TBS (OFF_TBF + NROWS * 20)
#define OFF_WP (OFF_TBS + NROWS * 20)
#define OFF_CF (OFF_WP + 512)
#define OFF_CS (OFF_CF + NROWS)
#define OFF_LISTS (OFF_CS + NROWS)
#define LF_CAP ((size_t)NROWS * MCOLS)

#define WP_W1 0
#define WP_B1 162
#define WP_W2 171
#define WP_B2 225
#define WP_W3 231
#define WP_B3 249
#define WP_SOLID 252

// 2*log2(e): folded into A/B rows and W1/b1/W2/b2 at prep (R14, +12%).
#define TANH_K 2.8853900817779268f

__device__ __forceinline__ float tanh_pre(float x) {
    float t = __builtin_amdgcn_exp2f(x);
    return 1.0f - 2.0f * __builtin_amdgcn_rcpf(1.0f + t);
}

// grouped reciprocals: 1 rcp for 4 (or 2) denominators, d >= 1 so no
// cancellation; rel err ~3e-7 (vs absmax margin 0.5 -> negligible).
__device__ __forceinline__ void inv4(float d0, float d1, float d2, float d3,
                                     float& i0, float& i1, float& i2, float& i3) {
    const float p01 = d0 * d1, p23 = d2 * d3;
    const float r = __builtin_amdgcn_rcpf(p01 * p23);
    const float r01 = r * p23, r23 = r * p01;
    i0 = r01 * d1; i1 = r01 * d0; i2 = r23 * d3; i3 = r23 * d2;
}
__device__ __forceinline__ void inv2(float d0, float d1, float& i0, float& i1) {
    const float r = __builtin_amdgcn_rcpf(d0 * d1);
    i0 = r * d1; i1 = r * d0;
}

// ---------- champion eval (R11 + R14): scalar + layer-ILP fences ----------
__device__ __forceinline__ void eval_regs_ilp(float4 P0, float4 P1, float4 P2,
                                              float4 P3, float2 P4,
                                              const float* __restrict__ Bq,
                                              const float* __restrict__ W,
                                              float& p0, float& p1, float& p2) {
    float h[18];
    h[0]  = tanh_pre(P0.x + Bq[0]);  h[1]  = tanh_pre(P0.y + Bq[1]);
    h[2]  = tanh_pre(P0.z + Bq[2]);  h[3]  = tanh_pre(P0.w + Bq[3]);
    h[4]  = tanh_pre(P1.x + Bq[4]);  h[5]  = tanh_pre(P1.y + Bq[5]);
    h[6]  = tanh_pre(P1.z + Bq[6]);  h[7]  = tanh_pre(P1.w + Bq[7]);
    h[8]  = tanh_pre(P2.x + Bq[8]);  h[9]  = tanh_pre(P2.y + Bq[9]);
    h[10] = tanh_pre(P2.z + Bq[10]); h[11] = tanh_pre(P2.w + Bq[11]);
    h[12] = tanh_pre(P3.x + Bq[12]); h[13] = tanh_pre(P3.y + Bq[13]);
    h[14] = tanh_pre(P3.z + Bq[14]); h[15] = tanh_pre(P3.w + Bq[15]);
    h[16] = tanh_pre(P4.x + Bq[16]); h[17] = tanh_pre(P4.y + Bq[17]);
    asm volatile("" : "+v"(h[0]), "+v"(h[1]), "+v"(h[2]), "+v"(h[3]),
                      "+v"(h[4]), "+v"(h[5]), "+v"(h[6]), "+v"(h[7]),
                      "+v"(h[8]), "+v"(h[9]), "+v"(h[10]), "+v"(h[11]),
                      "+v"(h[12]), "+v"(h[13]), "+v"(h[14]), "+v"(h[15]),
                      "+v"(h[16]), "+v"(h[17]));
    float g[9];
#pragma unroll
    for (int o = 0; o < 9; ++o) g[o] = W[WP_B1 + o];
#pragma unroll
    for (int j = 0; j < 18; ++j) {
        const float a = h[j];
#pragma unroll
        for (int o = 0; o < 9; ++o) g[o] += a * W[WP_W1 + j * 9 + o];
    }
#pragma unroll
    for (int o = 0; o < 9; ++o) g[o] = tanh_pre(g[o]);
    asm volatile("" : "+v"(g[0]), "+v"(g[1]), "+v"(g[2]), "+v"(g[3]),
                      "+v"(g[4]), "+v"(g[5]), "+v"(g[6]), "+v"(g[7]),
                      "+v"(g[8]));
    float q[6];
#pragma unroll
    for (int o = 0; o < 6; ++o) q[o] = W[WP_B2 + o];
#pragma unroll
    for (int j = 0; j < 9; ++j) {
        const float a = g[j];
#pragma unroll
        for (int o = 0; o < 6; ++o) q[o] += a * W[WP_W2 + j * 6 + o];
    }
#pragma unroll
    for (int o = 0; o < 6; ++o) q[o] = tanh_pre(q[o]);
    asm volatile("" : "+v"(q[0]), "+v"(q[1]), "+v"(q[2]), "+v"(q[3]),
                      "+v"(q[4]), "+v"(q[5]));
    float o0 = W[WP_B3 + 0], o1 = W[WP_B3 + 1], o2 = W[WP_B3 + 2];
#pragma unroll
    for (int j = 0; j < 6; ++j) {
        const float a = q[j];
        o0 += a * W[WP_W3 + j * 3 + 0];
        o1 += a * W[WP_W3 + j * 3 + 1];
        o2 += a * W[WP_W3 + j * 3 + 2];
    }
    p0 += o0; p1 += o1; p2 += o2;
}

// ---------- experiment eval: exp2-product layer 1 + grouped rcp ----------
// P regs hold tA = exp2(K*A[j]); Tb holds tB = exp2(K*B[j]).
// tanh(A+B) = 1 - 2/(1 + tA*tB): layer 1 has ZERO exp2 per eval.
__device__ __forceinline__ void eval_texp_ilp(float4 P0, float4 P1, float4 P2,
                                              float4 P3, float2 P4,
                                              const float* __restrict__ Tb,
                                              const float* __restrict__ W,
                                              float& p0, float& p1, float& p2) {
    const float d0  = fmaf(P0.x, Tb[0], 1.f);
    const float d1  = fmaf(P0.y, Tb[1], 1.f);
    const float d2  = fmaf(P0.z, Tb[2], 1.f);
    const float d3  = fmaf(P0.w, Tb[3], 1.f);
    const float d4  = fmaf(P1.x, Tb[4], 1.f);
    const float d5  = fmaf(P1.y, Tb[5], 1.f);
    const float d6  = fmaf(P1.z, Tb[6], 1.f);
    const float d7  = fmaf(P1.w, Tb[7], 1.f);
    const float d8  = fmaf(P2.x, Tb[8], 1.f);
    const float d9  = fmaf(P2.y, Tb[9], 1.f);
    const float d10 = fmaf(P2.z, Tb[10], 1.f);
    const float d11 = fmaf(P2.w, Tb[11], 1.f);
    const float d12 = fmaf(P3.x, Tb[12], 1.f);
    const float d13 = fmaf(P3.y, Tb[13], 1.f);
    const float d14 = fmaf(P3.z, Tb[14], 1.f);
    const float d15 = fmaf(P3.w, Tb[15], 1.f);
    const float d16 = fmaf(P4.x, Tb[16], 1.f);
    const float d17 = fmaf(P4.y, Tb[17], 1.f);
    float iv[18];
    inv4(d0, d1, d2, d3, iv[0], iv[1], iv[2], iv[3]);
    inv4(d4, d5, d6, d7, iv[4], iv[5], iv[6], iv[7]);
    inv4(d8, d9, d10, d11, iv[8], iv[9], iv[10], iv[11]);
    inv4(d12, d13, d14, d15, iv[12], iv[13], iv[14], iv[15]);
    inv2(d16, d17, iv[16], iv[17]);
    float h[18];
#pragma unroll
    for (int j = 0; j < 18; ++j) h[j] = fmaf(-2.f, iv[j], 1.f);
    asm volatile("" : "+v"(h[0]), "+v"(h[1]), "+v"(h[2]), "+v"(h[3]),
                      "+v"(h[4]), "+v"(h[5]), "+v"(h[6]), "+v"(h[7]),
                      "+v"(h[8]), "+v"(h[9]), "+v"(h[10]), "+v"(h[11]),
                      "+v"(h[12]), "+v"(h[13]), "+v"(h[14]), "+v"(h[15]),
                      "+v"(h[16]), "+v"(h[17]));
    float g[9];
#pragma unroll
    for (int o = 0; o < 9; ++o) g[o] = W[WP_B1 + o];
#pragma unroll
    for (int j = 0; j < 18; ++j) {
        const float a = h[j];
#pragma unroll
        for (int o = 0; o < 9; ++o) g[o] += a * W[WP_W1 + j * 9 + o];
    }
    // layer-2 tanh: 9 exp2 + grouped rcp
    {
        float e[9], dg[9], ig[9];
#pragma unroll
        for (int o = 0; o < 9; ++o) e[o] = __builtin_amdgcn_exp2f(g[o]);
#pragma unroll
        for (int o = 0; o < 9; ++o) dg[o] = e[o] + 1.f;
        inv4(dg[0], dg[1], dg[2], dg[3], ig[0], ig[1], ig[2], ig[3]);
        inv4(dg[4], dg[5], dg[6], dg[7], ig[4], ig[5], ig[6], ig[7]);
        ig[8] = __builtin_amdgcn_rcpf(dg[8]);
#pragma unroll
        for (int o = 0; o < 9; ++o) g[o] = fmaf(-2.f, ig[o], 1.f);
    }
    asm volatile("" : "+v"(g[0]), "+v"(g[1]), "+v"(g[2]), "+v"(g[3]),
                      "+v"(g[4]), "+v"(g[5]), "+v"(g[6]), "+v"(g[7]),
                      "+v"(g[8]));
    float q[6];
#pragma unroll
    for (int o = 0; o < 6; ++o) q[o] = W[WP_B2 + o];
#pragma unroll
    for (int j = 0; j < 9; ++j) {
        const float a = g[j];
#pragma unroll
        for (int o = 0; o < 6; ++o) q[o] += a * W[WP_W2 + j * 6 + o];
    }
    // layer-3 tanh: 6 exp2 + grouped rcp
    {
        float e[6], dq[6], iq[6];
#pragma unroll
        for (int o = 0; o < 6; ++o) e[o] = __builtin_amdgcn_exp2f(q[o]);
#pragma unroll
        for (int o = 0; o < 6; ++o) dq[o] = e[o] + 1.f;
        inv4(dq[0], dq[1], dq[2], dq[3], iq[0], iq[1], iq[2], iq[3]);
        inv2(dq[4], dq[5], iq[4], iq[5]);
#pragma unroll
        for (int o = 0; o < 6; ++o) q[o] = fmaf(-2.f, iq[o], 1.f);
    }
    asm volatile("" : "+v"(q[0]), "+v"(q[1]), "+v"(q[2]), "+v"(q[3]),
                      "+v"(q[4]), "+v"(q[5]));
    float o0 = W[WP_B3 + 0], o1 = W[WP_B3 + 1], o2 = W[WP_B3 + 2];
#pragma unroll
    for (int j = 0; j < 6; ++j) {
        const float a = q[j];
        o0 += a * W[WP_W3 + j * 3 + 0];
        o1 += a * W[WP_W3 + j * 3 + 1];
        o2 += a * W[WP_W3 + j * 3 + 2];
    }
    p0 += o0; p1 += o1; p2 += o2;
}

// loop: 2-deep register prefetch, eval selected by template flag.
template <int TEXP>
__device__ __forceinline__ void row_loop(const float* __restrict__ A,
                                         const unsigned short* __restrict__ lst,
                                         int cnt,
                                         const float* __restrict__ Bq,
                                         const float* __restrict__ W,
                                         int tid,
                                         float& p0, float& p1, float& p2) {
    int i = tid;
    if (i >= cnt) return;
    const float* r = A + (int)lst[i] * 20;
    float4 P0 = *(const float4*)(r);
    float4 P1 = *(const float4*)(r + 4);
    float4 P2 = *(const float4*)(r + 8);
    float4 P3 = *(const float4*)(r + 12);
    float2 P4 = *(const float2*)(r + 16);
    for (;;) {
        const int inext = i + 256;
        const bool more = inext < cnt;
        const float* rn = A + (int)lst[more ? inext : i] * 20;
        const float4 N0 = *(const float4*)(rn);
        const float4 N1 = *(const float4*)(rn + 4);
        const float4 N2 = *(const float4*)(rn + 8);
        const float4 N3 = *(const float4*)(rn + 12);
        const float2 N4 = *(const float2*)(rn + 16);
        if (TEXP) eval_texp_ilp(P0, P1, P2, P3, P4, Bq, W, p0, p1, p2);
        else      eval_regs_ilp(P0, P1, P2, P3, P4, Bq, W, p0, p1, p2);
        if (!more) break;
        P0 = N0; P1 = N1; P2 = N2; P3 = N3; P4 = N4;
        i = inext;
    }
}

__global__ void prep_kernel(const int* __restrict__ index,
                            const float* __restrict__ data,
                            const float* __restrict__ wf0, const float* __restrict__ bf0,
                            const float* __restrict__ sw0, const float* __restrict__ sb0,
                            const float* __restrict__ wf1, const float* __restrict__ bf1,
                            const float* __restrict__ wf2, const float* __restrict__ bf2,
                            const float* __restrict__ wf3, const float* __restrict__ bf3,
                            const float* __restrict__ sw1, const float* __restrict__ sb1,
                            const float* __restrict__ sw2, const float* __restrict__ sb2,
                            const float* __restrict__ sw3, const float* __restrict__ sb3,
                            float* __restrict__ wsp) {
    int i = blockIdx.x * blockDim.x + threadIdx.x;
    if (i < NROWS) {
        float d[7], cen[7];
#pragma unroll
        for (int c = 0; c < 7; ++c) d[c] = data[i * 7 + c];
        int ci = index[i];
#pragma unroll
        for (int c = 0; c < 7; ++c) cen[c] = data[ci * 7 + c];
#pragma unroll
        for (int j = 0; j < 18; ++j) {
            float af = 0.f;
#pragma unroll
            for (int c = 0; c < 7; ++c) af += d[c] * wf0[c * 18 + j];
            float as = d[0] * sw0[0 * 18 + j] + d[1] * sw0[1 * 18 + j] + d[2] * sw0[2 * 18 + j];
            float bf = bf0[j], bs = sb0[j];
#pragma unroll
            for (int c = 0; c < 3; ++c) bf -= cen[c] * wf0[c * 18 + j];
#pragma unroll
            for (int c = 0; c < 4; ++c) bf += cen[3 + c] * wf0[(7 + c) * 18 + j];
#pragma unroll
            for (int c = 0; c < 3; ++c) bs -= cen[c] * sw0[c * 18 + j];
#pragma unroll
            for (int c = 0; c < 4; ++c) bs += cen[3 + c] * sw0[(3 + c) * 18 + j];
            const float afk = af * TANH_K, ask = as * TANH_K;
            const float bfk = bf * TANH_K, bsk = bs * TANH_K;
            // sum-form (champion)
            wsp[OFF_AF + i * 20 + j] = afk;
            wsp[OFF_AS + i * 20 + j] = ask;
            wsp[OFF_BF + i * 20 + j] = bfk;
            wsp[OFF_BS + i * 20 + j] = bsk;
            // exp-form (experiment): tanh(A+B) needs only tA*tB
            wsp[OFF_TAF + i * 20 + j] = __builtin_amdgcn_exp2f(afk);
            wsp[OFF_TAS + i * 20 + j] = __builtin_amdgcn_exp2f(ask);
            wsp[OFF_TBF + i * 20 + j] = __builtin_amdgcn_exp2f(bfk);
            wsp[OFF_TBS + i * 20 + j] = __builtin_amdgcn_exp2f(bsk);
        }
        wsp[OFF_AF + i * 20 + 18] = 0.f; wsp[OFF_AF + i * 20 + 19] = 0.f;
        wsp[OFF_AS + i * 20 + 18] = 0.f; wsp[OFF_AS + i * 20 + 19] = 0.f;
        wsp[OFF_BF + i * 20 + 18] = 0.f; wsp[OFF_BF + i * 20 + 19] = 0.f;
        wsp[OFF_BS + i * 20 + 18] = 0.f; wsp[OFF_BS + i * 20 + 19] = 0.f;
        wsp[OFF_TAF + i * 20 + 18] = 0.f; wsp[OFF_TAF + i * 20 + 19] = 0.f;
        wsp[OFF_TAS + i * 20 + 18] = 0.f; wsp[OFF_TAS + i * 20 + 19] = 0.f;
        wsp[OFF_TBF + i * 20 + 18] = 0.f; wsp[OFF_TBF + i * 20 + 19] = 0.f;
        wsp[OFF_TBS + i * 20 + 18] = 0.f; wsp[OFF_TBS + i * 20 + 19] = 0.f;
    }
    if (blockIdx.x == 0) {
        int t = threadIdx.x;
        float* wp = wsp + OFF_WP;
        for (int k = t; k < 162; k += 256) wp[WP_W1 + k] = wf1[k] * TANH_K;
        for (int k = t; k < 9;   k += 256) wp[WP_B1 + k] = bf1[k] * TANH_K;
        for (int k = t; k < 54;  k += 256) wp[WP_W2 + k] = wf2[k] * TANH_K;
        for (int k = t; k < 6;   k += 256) wp[WP_B2 + k] = bf2[k] * TANH_K;
        for (int k = t; k < 18;  k += 256) wp[WP_W3 + k] = wf3[k];
        for (int k = t; k < 3;   k += 256) wp[WP_B3 + k] = bf3[k];
        for (int k = t; k < 162; k += 256) wp[WP_SOLID + WP_W1 + k] = sw1[k] * TANH_K;
        for (int k = t; k < 9;   k += 256) wp[WP_SOLID + WP_B1 + k] = sb1[k] * TANH_K;
        for (int k = t; k < 54;  k += 256) wp[WP_SOLID + WP_W2 + k] = sw2[k] * TANH_K;
        for (int k = t; k < 6;   k += 256) wp[WP_SOLID + WP_B2 + k] = sb2[k] * TANH_K;
        for (int k = t; k < 18;  k += 256) wp[WP_SOLID + WP_W3 + k] = sw3[k];
        for (int k = t; k < 3;   k += 256) wp[WP_SOLID + WP_B3 + k] = sb3[k];
    }
}

__global__ __launch_bounds__(256)
void compact_kernel(const int* __restrict__ mask,
                    const float* __restrict__ data,
                    float* __restrict__ wsp) {
    const int lane = threadIdx.x & 63;
    const int n = blockIdx.x * 4 + (threadIdx.x >> 6);
    int* counts_f = (int*)(wsp + OFF_CF);
    int* counts_s = (int*)(wsp + OFF_CS);
    unsigned short* lf = (unsigned short*)(wsp + OFF_LISTS) + (size_t)n * MCOLS;
    unsigned short* ls = lf + LF_CAP;
    const int* mrow = mask + (size_t)n * MCOLS;
    int bf = 0, bs = 0;
    const unsigned long long ltmask = (1ull << lane) - 1ull;
#pragma unroll 1
    for (int it = 0; it < MCOLS / 64; ++it) {
        const int m = it * 64 + lane;
        const int mk = mrow[m];
        const float flag = data[m * 7 + 6];
        const bool af = mk && (flag > 0.f);
        const bool as = mk && (flag < 1.f);
        const unsigned long long balf = __ballot(af);
        const unsigned long long bals = __ballot(as);
        if (af) lf[bf + __popcll(balf & ltmask)] = (unsigned short)m;
        if (as) ls[bs + __popcll(bals & ltmask)] = (unsigned short)m;
        bf += __popcll(balf);
        bs += __popcll(bals);
    }
    if (lane == 0) { counts_f[n] = bf; counts_s[n] = bs; }
}

template <int TEXP>
__device__ __forceinline__ void main_body(const float* __restrict__ wsp,
                                          float* __restrict__ out) {
    const int n = blockIdx.x;
    const int tid = threadIdx.x;
    __shared__ float red[3][4];
    const float* __restrict__ W = wsp + OFF_WP;
    const int cf = ((const int*)(wsp + OFF_CF))[n];
    const int cs = ((const int*)(wsp + OFF_CS))[n];
    const unsigned short* lf = (const unsigned short*)(wsp + OFF_LISTS) + (size_t)n * MCOLS;
    const unsigned short* ls = lf + LF_CAP;

    float p0 = 0.f, p1 = 0.f, p2 = 0.f;
    if (TEXP) {
        row_loop<1>(wsp + OFF_TAF, lf, cf, wsp + OFF_TBF + n * 20, W, tid, p0, p1, p2);
        row_loop<1>(wsp + OFF_TAS, ls, cs, wsp + OFF_TBS + n * 20, W + WP_SOLID, tid, p0, p1, p2);
    } else {
        row_loop<0>(wsp + OFF_AF, lf, cf, wsp + OFF_BF + n * 20, W, tid, p0, p1, p2);
        row_loop<0>(wsp + OFF_AS, ls, cs, wsp + OFF_BS + n * 20, W + WP_SOLID, tid, p0, p1, p2);
    }

#pragma unroll
    for (int off = 32; off > 0; off >>= 1) {
        p0 += __shfl_xor(p0, off, 64);
        p1 += __shfl_xor(p1, off, 64);
        p2 += __shfl_xor(p2, off, 64);
    }
    const int wid = tid >> 6;
    if ((tid & 63) == 0) { red[0][wid] = p0; red[1][wid] = p1; red[2][wid] = p2; }
    __syncthreads();
    if (tid == 0) {
        float a0 = 0.f, a1 = 0.f, a2 = 0.f;
#pragma unroll
        for (int w = 0; w < 4; ++w) { a0 += red[0][w]; a1 += red[1][w]; a2 += red[2][w]; }
        out[n * 3 + 0] = a0; out[n * 3 + 1] = a1; out[n * 3 + 2] = a2;
    }
}

// R16 A/B: trans-reduction (exp2-product + grouped rcp) vs champion.
// Champion runs LAST -> validated.
__global__ __launch_bounds__(256, 4)
void main_texp(const float* __restrict__ wsp, float* __restrict__ out) {
    main_body<1>(wsp, out);
}

__global__ __launch_bounds__(256, 4)
void main_ilp(const float* __restrict__ wsp, float* __restrict__ out) {
    main_body<0>(wsp, out);
}

extern "C" void kernel_launch(void* const* d_in, const int* in_sizes, int n_in,
                              void* d_out, int out_size, void* d_ws, size_t ws_size,
                              hipStream_t stream) {
    const int*   mask  = (const int*)d_in[0];
    const int*   index = (const int*)d_in[1];
    const float* data  = (const float*)d_in[2];
    const float* wf0   = (const float*)d_in[3];
    const float* bf0   = (const float*)d_in[4];
    const float* wf1   = (const float*)d_in[5];
    const float* bf1   = (const float*)d_in[6];
    const float* wf2   = (const float*)d_in[7];
    const float* bf2   = (const float*)d_in[8];
    const float* wf3   = (const float*)d_in[9];
    const float* bf3   = (const float*)d_in[10];
    const float* sw0   = (const float*)d_in[11];
    const float* sb0   = (const float*)d_in[12];
    const float* sw1   = (const float*)d_in[13];
    const float* sb1   = (const float*)d_in[14];
    const float* sw2   = (const float*)d_in[15];
    const float* sb2   = (const float*)d_in[16];
    const float* sw3   = (const float*)d_in[17];
    const float* sb3   = (const float*)d_in[18];
    float* wsp = (float*)d_ws;
    float* out = (float*)d_out;

    prep_kernel<<<dim3(8), dim3(256), 0, stream>>>(
        index, data, wf0, bf0, sw0, sb0, wf1, bf1, wf2, bf2, wf3, bf3,
        sw1, sb1, sw2, sb2, sw3, sb3, wsp);
    compact_kernel<<<dim3(NROWS / 4), dim3(256), 0, stream>>>(mask, data, wsp);
    main_texp<<<dim3(NROWS), dim3(256), 0, stream>>>(wsp, out);
    main_ilp<<<dim3(NROWS), dim3(256), 0, stream>>>(wsp, out);
}

// Round 17
// 69.391 us; speedup vs baseline: 1.7257x; 1.7257x over previous
//
#include <hip/hip_runtime.h>

#define NROWS 2048
#define MCOLS 2048

// ---- d_ws layout (float offsets); rows padded to stride 20 ----
#define OFF_AF 0
#define OFF_AS (OFF_AF + NROWS * 20)
#define OFF_BF (OFF_AS + NROWS * 20)
#define OFF_BS (OFF_BF + NROWS * 20)
#define OFF_WP (OFF_BS + NROWS * 20)
#define OFF_CF (OFF_WP + 512)
#define OFF_CS (OFF_CF + NROWS)
#define OFF_LISTS (OFF_CS + NROWS)
#define LF_CAP ((size_t)NROWS * MCOLS)

#define WP_W1 0
#define WP_B1 162
#define WP_W2 171
#define WP_B2 225
#define WP_W3 231
#define WP_B3 249
#define WP_SOLID 252

// 2*log2(e): folded into A/B rows and W1/b1/W2/b2 at prep (R14, +12%).
#define TANH_K 2.8853900817779268f

// tanh with the scale pre-folded: tanh(x) = 1 - 2/(1 + 2^(K x)).
__device__ __forceinline__ float tanh_pre(float x) {
    float t = __builtin_amdgcn_exp2f(x);
    return 1.0f - 2.0f * __builtin_amdgcn_rcpf(1.0f + t);
}

// Champion eval (R11 + R14): scalar math + layer-ILP asm fences.
// Fences force all 18/9/6 activations simultaneously live so the compiler
// cannot re-serialize the independent tanh chains to save VGPRs (that
// serialization was the hidden 1.7x cost through R10). Weight/bias reads are
// block-uniform -> s_load (R4); W1/b1/W2/b2 arrive pre-scaled by TANH_K.
// Closed levers (measured, do not revisit): occupancy>4 (R7/R14), pk-packing
// (R8/R12), dual-eval ILP (R15), LDS tiling (R10), trans-reduction (R16).
__device__ __forceinline__ void eval_regs_ilp(float4 P0, float4 P1, float4 P2,
                                              float4 P3, float2 P4,
                                              const float* __restrict__ Bq,
                                              const float* __restrict__ W,
                                              float& p0, float& p1, float& p2) {
    float h[18];
    h[0]  = tanh_pre(P0.x + Bq[0]);  h[1]  = tanh_pre(P0.y + Bq[1]);
    h[2]  = tanh_pre(P0.z + Bq[2]);  h[3]  = tanh_pre(P0.w + Bq[3]);
    h[4]  = tanh_pre(P1.x + Bq[4]);  h[5]  = tanh_pre(P1.y + Bq[5]);
    h[6]  = tanh_pre(P1.z + Bq[6]);  h[7]  = tanh_pre(P1.w + Bq[7]);
    h[8]  = tanh_pre(P2.x + Bq[8]);  h[9]  = tanh_pre(P2.y + Bq[9]);
    h[10] = tanh_pre(P2.z + Bq[10]); h[11] = tanh_pre(P2.w + Bq[11]);
    h[12] = tanh_pre(P3.x + Bq[12]); h[13] = tanh_pre(P3.y + Bq[13]);
    h[14] = tanh_pre(P3.z + Bq[14]); h[15] = tanh_pre(P3.w + Bq[15]);
    h[16] = tanh_pre(P4.x + Bq[16]); h[17] = tanh_pre(P4.y + Bq[17]);
    asm volatile("" : "+v"(h[0]), "+v"(h[1]), "+v"(h[2]), "+v"(h[3]),
                      "+v"(h[4]), "+v"(h[5]), "+v"(h[6]), "+v"(h[7]),
                      "+v"(h[8]), "+v"(h[9]), "+v"(h[10]), "+v"(h[11]),
                      "+v"(h[12]), "+v"(h[13]), "+v"(h[14]), "+v"(h[15]),
                      "+v"(h[16]), "+v"(h[17]));
    float g[9];
#pragma unroll
    for (int o = 0; o < 9; ++o) g[o] = W[WP_B1 + o];
#pragma unroll
    for (int j = 0; j < 18; ++j) {
        const float a = h[j];
#pragma unroll
        for (int o = 0; o < 9; ++o) g[o] += a * W[WP_W1 + j * 9 + o];
    }
#pragma unroll
    for (int o = 0; o < 9; ++o) g[o] = tanh_pre(g[o]);
    asm volatile("" : "+v"(g[0]), "+v"(g[1]), "+v"(g[2]), "+v"(g[3]),
                      "+v"(g[4]), "+v"(g[5]), "+v"(g[6]), "+v"(g[7]),
                      "+v"(g[8]));
    float q[6];
#pragma unroll
    for (int o = 0; o < 6; ++o) q[o] = W[WP_B2 + o];
#pragma unroll
    for (int j = 0; j < 9; ++j) {
        const float a = g[j];
#pragma unroll
        for (int o = 0; o < 6; ++o) q[o] += a * W[WP_W2 + j * 6 + o];
    }
#pragma unroll
    for (int o = 0; o < 6; ++o) q[o] = tanh_pre(q[o]);
    asm volatile("" : "+v"(q[0]), "+v"(q[1]), "+v"(q[2]), "+v"(q[3]),
                      "+v"(q[4]), "+v"(q[5]));
    float o0 = W[WP_B3 + 0], o1 = W[WP_B3 + 1], o2 = W[WP_B3 + 2];
#pragma unroll
    for (int j = 0; j < 6; ++j) {
        const float a = q[j];
        o0 += a * W[WP_W3 + j * 3 + 0];
        o1 += a * W[WP_W3 + j * 3 + 1];
        o2 += a * W[WP_W3 + j * 3 + 2];
    }
    p0 += o0; p1 += o1; p2 += o2;
}

// champion loop: scalar ILP eval + 2-deep register prefetch of next A-row.
__device__ __forceinline__ void row_loop_ilp(const float* __restrict__ A,
                                             const unsigned short* __restrict__ lst,
                                             int cnt,
                                             const float* __restrict__ Bq,
                                             const float* __restrict__ W,
                                             int tid,
                                             float& p0, float& p1, float& p2) {
    int i = tid;
    if (i >= cnt) return;
    const float* r = A + (int)lst[i] * 20;
    float4 P0 = *(const float4*)(r);
    float4 P1 = *(const float4*)(r + 4);
    float4 P2 = *(const float4*)(r + 8);
    float4 P3 = *(const float4*)(r + 12);
    float2 P4 = *(const float2*)(r + 16);
    for (;;) {
        const int inext = i + 256;
        const bool more = inext < cnt;
        const float* rn = A + (int)lst[more ? inext : i] * 20;
        const float4 N0 = *(const float4*)(rn);
        const float4 N1 = *(const float4*)(rn + 4);
        const float4 N2 = *(const float4*)(rn + 8);
        const float4 N3 = *(const float4*)(rn + 12);
        const float2 N4 = *(const float2*)(rn + 16);
        eval_regs_ilp(P0, P1, P2, P3, P4, Bq, W, p0, p1, p2);
        if (!more) break;
        P0 = N0; P1 = N1; P2 = N2; P3 = N3; P4 = N4;
        i = inext;
    }
}

__global__ void prep_kernel(const int* __restrict__ index,
                            const float* __restrict__ data,
                            const float* __restrict__ wf0, const float* __restrict__ bf0,
                            const float* __restrict__ sw0, const float* __restrict__ sb0,
                            const float* __restrict__ wf1, const float* __restrict__ bf1,
                            const float* __restrict__ wf2, const float* __restrict__ bf2,
                            const float* __restrict__ wf3, const float* __restrict__ bf3,
                            const float* __restrict__ sw1, const float* __restrict__ sb1,
                            const float* __restrict__ sw2, const float* __restrict__ sb2,
                            const float* __restrict__ sw3, const float* __restrict__ sb3,
                            float* __restrict__ wsp) {
    int i = blockIdx.x * blockDim.x + threadIdx.x;
    if (i < NROWS) {
        float d[7], cen[7];
#pragma unroll
        for (int c = 0; c < 7; ++c) d[c] = data[i * 7 + c];
        int ci = index[i];
#pragma unroll
        for (int c = 0; c < 7; ++c) cen[c] = data[ci * 7 + c];
#pragma unroll
        for (int j = 0; j < 18; ++j) {
            float af = 0.f;
#pragma unroll
            for (int c = 0; c < 7; ++c) af += d[c] * wf0[c * 18 + j];
            float as = d[0] * sw0[0 * 18 + j] + d[1] * sw0[1 * 18 + j] + d[2] * sw0[2 * 18 + j];
            float bf = bf0[j], bs = sb0[j];
#pragma unroll
            for (int c = 0; c < 3; ++c) bf -= cen[c] * wf0[c * 18 + j];
#pragma unroll
            for (int c = 0; c < 4; ++c) bf += cen[3 + c] * wf0[(7 + c) * 18 + j];
#pragma unroll
            for (int c = 0; c < 3; ++c) bs -= cen[c] * sw0[c * 18 + j];
#pragma unroll
            for (int c = 0; c < 4; ++c) bs += cen[3 + c] * sw0[(3 + c) * 18 + j];
            wsp[OFF_AF + i * 20 + j] = af * TANH_K;
            wsp[OFF_AS + i * 20 + j] = as * TANH_K;
            wsp[OFF_BF + i * 20 + j] = bf * TANH_K;
            wsp[OFF_BS + i * 20 + j] = bs * TANH_K;
        }
        wsp[OFF_AF + i * 20 + 18] = 0.f; wsp[OFF_AF + i * 20 + 19] = 0.f;
        wsp[OFF_AS + i * 20 + 18] = 0.f; wsp[OFF_AS + i * 20 + 19] = 0.f;
        wsp[OFF_BF + i * 20 + 18] = 0.f; wsp[OFF_BF + i * 20 + 19] = 0.f;
        wsp[OFF_BS + i * 20 + 18] = 0.f; wsp[OFF_BS + i * 20 + 19] = 0.f;
    }
    if (blockIdx.x == 0) {
        int t = threadIdx.x;
        float* wp = wsp + OFF_WP;
        for (int k = t; k < 162; k += 256) wp[WP_W1 + k] = wf1[k] * TANH_K;
        for (int k = t; k < 9;   k += 256) wp[WP_B1 + k] = bf1[k] * TANH_K;
        for (int k = t; k < 54;  k += 256) wp[WP_W2 + k] = wf2[k] * TANH_K;
        for (int k = t; k < 6;   k += 256) wp[WP_B2 + k] = bf2[k] * TANH_K;
        for (int k = t; k < 18;  k += 256) wp[WP_W3 + k] = wf3[k];
        for (int k = t; k < 3;   k += 256) wp[WP_B3 + k] = bf3[k];
        for (int k = t; k < 162; k += 256) wp[WP_SOLID + WP_W1 + k] = sw1[k] * TANH_K;
        for (int k = t; k < 9;   k += 256) wp[WP_SOLID + WP_B1 + k] = sb1[k] * TANH_K;
        for (int k = t; k < 54;  k += 256) wp[WP_SOLID + WP_W2 + k] = sw2[k] * TANH_K;
        for (int k = t; k < 6;   k += 256) wp[WP_SOLID + WP_B2 + k] = sb2[k] * TANH_K;
        for (int k = t; k < 18;  k += 256) wp[WP_SOLID + WP_W3 + k] = sw3[k];
        for (int k = t; k < 3;   k += 256) wp[WP_SOLID + WP_B3 + k] = sb3[k];
    }
}

__global__ __launch_bounds__(256)
void compact_kernel(const int* __restrict__ mask,
                    const float* __restrict__ data,
                    float* __restrict__ wsp) {
    const int lane = threadIdx.x & 63;
    const int n = blockIdx.x * 4 + (threadIdx.x >> 6);
    int* counts_f = (int*)(wsp + OFF_CF);
    int* counts_s = (int*)(wsp + OFF_CS);
    unsigned short* lf = (unsigned short*)(wsp + OFF_LISTS) + (size_t)n * MCOLS;
    unsigned short* ls = lf + LF_CAP;
    const int* mrow = mask + (size_t)n * MCOLS;
    int bf = 0, bs = 0;
    const unsigned long long ltmask = (1ull << lane) - 1ull;
#pragma unroll 1
    for (int it = 0; it < MCOLS / 64; ++it) {
        const int m = it * 64 + lane;
        const int mk = mrow[m];
        const float flag = data[m * 7 + 6];
        const bool af = mk && (flag > 0.f);
        const bool as = mk && (flag < 1.f);
        const unsigned long long balf = __ballot(af);
        const unsigned long long bals = __ballot(as);
        if (af) lf[bf + __popcll(balf & ltmask)] = (unsigned short)m;
        if (as) ls[bs + __popcll(bals & ltmask)] = (unsigned short)m;
        bf += __popcll(balf);
        bs += __popcll(bals);
    }
    if (lane == 0) { counts_f[n] = bf; counts_s[n] = bs; }
}

// Champion (R11 ILP fences + R14 TANH_K fold), single kernel — clean ship.
__global__ __launch_bounds__(256, 4)
void main_ilp(const float* __restrict__ wsp, float* __restrict__ out) {
    const int n = blockIdx.x;
    const int tid = threadIdx.x;
    __shared__ float red[3][4];
    const float* __restrict__ W  = wsp + OFF_WP;
    const float* __restrict__ Bf = wsp + OFF_BF + n * 20;
    const float* __restrict__ Bs = wsp + OFF_BS + n * 20;
    const int cf = ((const int*)(wsp + OFF_CF))[n];
    const int cs = ((const int*)(wsp + OFF_CS))[n];
    const unsigned short* lf = (const unsigned short*)(wsp + OFF_LISTS) + (size_t)n * MCOLS;
    const unsigned short* ls = lf + LF_CAP;

    float p0 = 0.f, p1 = 0.f, p2 = 0.f;
    row_loop_ilp(wsp + OFF_AF, lf, cf, Bf, W, tid, p0, p1, p2);
    row_loop_ilp(wsp + OFF_AS, ls, cs, Bs, W + WP_SOLID, tid, p0, p1, p2);

#pragma unroll
    for (int off = 32; off > 0; off >>= 1) {
        p0 += __shfl_xor(p0, off, 64);
        p1 += __shfl_xor(p1, off, 64);
        p2 += __shfl_xor(p2, off, 64);
    }
    const int wid = tid >> 6;
    if ((tid & 63) == 0) { red[0][wid] = p0; red[1][wid] = p1; red[2][wid] = p2; }
    __syncthreads();
    if (tid == 0) {
        float a0 = 0.f, a1 = 0.f, a2 = 0.f;
#pragma unroll
        for (int w = 0; w < 4; ++w) { a0 += red[0][w]; a1 += red[1][w]; a2 += red[2][w]; }
        out[n * 3 + 0] = a0; out[n * 3 + 1] = a1; out[n * 3 + 2] = a2;
    }
}

extern "C" void kernel_launch(void* const* d_in, const int* in_sizes, int n_in,
                              void* d_out, int out_size, void* d_ws, size_t ws_size,
                              hipStream_t stream) {
    const int*   mask  = (const int*)d_in[0];
    const int*   index = (const int*)d_in[1];
    const float* data  = (const float*)d_in[2];
    const float* wf0   = (const float*)d_in[3];
    const float* bf0   = (const float*)d_in[4];
    const float* wf1   = (const float*)d_in[5];
    const float* bf1   = (const float*)d_in[6];
    const float* wf2   = (const float*)d_in[7];
    const float* bf2   = (const float*)d_in[8];
    const float* wf3   = (const float*)d_in[9];
    const float* bf3   = (const float*)d_in[10];
    const float* sw0   = (const float*)d_in[11];
    const float* sb0   = (const float*)d_in[12];
    const float* sw1   = (const float*)d_in[13];
    const float* sb1   = (const float*)d_in[14];
    const float* sw2   = (const float*)d_in[15];
    const float* sb2   = (const float*)d_in[16];
    const float* sw3   = (const float*)d_in[17];
    const float* sb3   = (const float*)d_in[18];
    float* wsp = (float*)d_ws;
    float* out = (float*)d_out;

    prep_kernel<<<dim3(8), dim3(256), 0, stream>>>(
        index, data, wf0, bf0, sw0, sb0, wf1, bf1, wf2, bf2, wf3, bf3,
        sw1, sb1, sw2, sb2, sw3, sb3, wsp);
    compact_kernel<<<dim3(NROWS / 4), dim3(256), 0, stream>>>(mask, data, wsp);
    main_ilp<<<dim3(NROWS), dim3(256), 0, stream>>>(wsp, out);
}

// Round 18
// 60.251 us; speedup vs baseline: 1.9875x; 1.1517x over previous
//
#include <hip/hip_runtime.h>

#define NROWS 2048
#define MCOLS 2048

// ---- d_ws layout (float offsets); rows padded to stride 20 ----
#define OFF_AF 0
#define OFF_AS (OFF_AF + NROWS * 20)
#define OFF_BF (OFF_AS + NROWS * 20)
#define OFF_BS (OFF_BF + NROWS * 20)
#define OFF_WP (OFF_BS + NROWS * 20)
#define OFF_FB (OFF_WP + 512)   // u64[32]: fluid bit per m (flag>0)
#define OFF_SB (OFF_FB + 64)    // u64[32]: solid bit per m (flag<1)

#define WP_W1 0
#define WP_B1 162
#define WP_W2 171
#define WP_B2 225
#define WP_W3 231
#define WP_B3 249
#define WP_SOLID 252

// 2*log2(e): folded into A/B rows and W1/b1/W2/b2 at prep (R14, +12%).
#define TANH_K 2.8853900817779268f

// tanh with the scale pre-folded: tanh(x) = 1 - 2/(1 + 2^(K x)).
__device__ __forceinline__ float tanh_pre(float x) {
    float t = __builtin_amdgcn_exp2f(x);
    return 1.0f - 2.0f * __builtin_amdgcn_rcpf(1.0f + t);
}

// Champion eval (R11 + R14): scalar math + layer-ILP asm fences.
// Fences force all 18/9/6 activations simultaneously live so the compiler
// cannot re-serialize the independent tanh chains (hidden 1.7x cost through
// R10). Weight/bias reads are block-uniform -> s_load. Closed levers
// (measured, do not revisit): occupancy>4 (R7/R14), pk-packing (R8/R12),
// dual-eval ILP (R15), LDS tiling (R10), trans-reduction (R16).
__device__ __forceinline__ void eval_regs_ilp(float4 P0, float4 P1, float4 P2,
                                              float4 P3, float2 P4,
                                              const float* __restrict__ Bq,
                                              const float* __restrict__ W,
                                              float& p0, float& p1, float& p2) {
    float h[18];
    h[0]  = tanh_pre(P0.x + Bq[0]);  h[1]  = tanh_pre(P0.y + Bq[1]);
    h[2]  = tanh_pre(P0.z + Bq[2]);  h[3]  = tanh_pre(P0.w + Bq[3]);
    h[4]  = tanh_pre(P1.x + Bq[4]);  h[5]  = tanh_pre(P1.y + Bq[5]);
    h[6]  = tanh_pre(P1.z + Bq[6]);  h[7]  = tanh_pre(P1.w + Bq[7]);
    h[8]  = tanh_pre(P2.x + Bq[8]);  h[9]  = tanh_pre(P2.y + Bq[9]);
    h[10] = tanh_pre(P2.z + Bq[10]); h[11] = tanh_pre(P2.w + Bq[11]);
    h[12] = tanh_pre(P3.x + Bq[12]); h[13] = tanh_pre(P3.y + Bq[13]);
    h[14] = tanh_pre(P3.z + Bq[14]); h[15] = tanh_pre(P3.w + Bq[15]);
    h[16] = tanh_pre(P4.x + Bq[16]); h[17] = tanh_pre(P4.y + Bq[17]);
    asm volatile("" : "+v"(h[0]), "+v"(h[1]), "+v"(h[2]), "+v"(h[3]),
                      "+v"(h[4]), "+v"(h[5]), "+v"(h[6]), "+v"(h[7]),
                      "+v"(h[8]), "+v"(h[9]), "+v"(h[10]), "+v"(h[11]),
                      "+v"(h[12]), "+v"(h[13]), "+v"(h[14]), "+v"(h[15]),
                      "+v"(h[16]), "+v"(h[17]));
    float g[9];
#pragma unroll
    for (int o = 0; o < 9; ++o) g[o] = W[WP_B1 + o];
#pragma unroll
    for (int j = 0; j < 18; ++j) {
        const float a = h[j];
#pragma unroll
        for (int o = 0; o < 9; ++o) g[o] += a * W[WP_W1 + j * 9 + o];
    }
#pragma unroll
    for (int o = 0; o < 9; ++o) g[o] = tanh_pre(g[o]);
    asm volatile("" : "+v"(g[0]), "+v"(g[1]), "+v"(g[2]), "+v"(g[3]),
                      "+v"(g[4]), "+v"(g[5]), "+v"(g[6]), "+v"(g[7]),
                      "+v"(g[8]));
    float q[6];
#pragma unroll
    for (int o = 0; o < 6; ++o) q[o] = W[WP_B2 + o];
#pragma unroll
    for (int j = 0; j < 9; ++j) {
        const float a = g[j];
#pragma unroll
        for (int o = 0; o < 6; ++o) q[o] += a * W[WP_W2 + j * 6 + o];
    }
#pragma unroll
    for (int o = 0; o < 6; ++o) q[o] = tanh_pre(q[o]);
    asm volatile("" : "+v"(q[0]), "+v"(q[1]), "+v"(q[2]), "+v"(q[3]),
                      "+v"(q[4]), "+v"(q[5]));
    float o0 = W[WP_B3 + 0], o1 = W[WP_B3 + 1], o2 = W[WP_B3 + 2];
#pragma unroll
    for (int j = 0; j < 6; ++j) {
        const float a = q[j];
        o0 += a * W[WP_W3 + j * 3 + 0];
        o1 += a * W[WP_W3 + j * 3 + 1];
        o2 += a * W[WP_W3 + j * 3 + 2];
    }
    p0 += o0; p1 += o1; p2 += o2;
}

// champion loop: scalar ILP eval + 2-deep register prefetch of next A-row.
// lst may point to LDS (fused path) or global; same code.
__device__ __forceinline__ void row_loop_ilp(const float* __restrict__ A,
                                             const unsigned short* lst,
                                             int cnt,
                                             const float* __restrict__ Bq,
                                             const float* __restrict__ W,
                                             int tid,
                                             float& p0, float& p1, float& p2) {
    int i = tid;
    if (i >= cnt) return;
    const float* r = A + (int)lst[i] * 20;
    float4 P0 = *(const float4*)(r);
    float4 P1 = *(const float4*)(r + 4);
    float4 P2 = *(const float4*)(r + 8);
    float4 P3 = *(const float4*)(r + 12);
    float2 P4 = *(const float2*)(r + 16);
    for (;;) {
        const int inext = i + 256;
        const bool more = inext < cnt;
        const float* rn = A + (int)lst[more ? inext : i] * 20;
        const float4 N0 = *(const float4*)(rn);
        const float4 N1 = *(const float4*)(rn + 4);
        const float4 N2 = *(const float4*)(rn + 8);
        const float4 N3 = *(const float4*)(rn + 12);
        const float2 N4 = *(const float2*)(rn + 16);
        eval_regs_ilp(P0, P1, P2, P3, P4, Bq, W, p0, p1, p2);
        if (!more) break;
        P0 = N0; P1 = N1; P2 = N2; P3 = N3; P4 = N4;
        i = inext;
    }
}

__global__ void prep_kernel(const int* __restrict__ index,
                            const float* __restrict__ data,
                            const float* __restrict__ wf0, const float* __restrict__ bf0,
                            const float* __restrict__ sw0, const float* __restrict__ sb0,
                            const float* __restrict__ wf1, const float* __restrict__ bf1,
                            const float* __restrict__ wf2, const float* __restrict__ bf2,
                            const float* __restrict__ wf3, const float* __restrict__ bf3,
                            const float* __restrict__ sw1, const float* __restrict__ sb1,
                            const float* __restrict__ sw2, const float* __restrict__ sb2,
                            const float* __restrict__ sw3, const float* __restrict__ sb3,
                            float* __restrict__ wsp) {
    int i = blockIdx.x * blockDim.x + threadIdx.x;
    if (i < NROWS) {
        float d[7], cen[7];
#pragma unroll
        for (int c = 0; c < 7; ++c) d[c] = data[i * 7 + c];
        int ci = index[i];
#pragma unroll
        for (int c = 0; c < 7; ++c) cen[c] = data[ci * 7 + c];
#pragma unroll
        for (int j = 0; j < 18; ++j) {
            float af = 0.f;
#pragma unroll
            for (int c = 0; c < 7; ++c) af += d[c] * wf0[c * 18 + j];
            float as = d[0] * sw0[0 * 18 + j] + d[1] * sw0[1 * 18 + j] + d[2] * sw0[2 * 18 + j];
            float bf = bf0[j], bs = sb0[j];
#pragma unroll
            for (int c = 0; c < 3; ++c) bf -= cen[c] * wf0[c * 18 + j];
#pragma unroll
            for (int c = 0; c < 4; ++c) bf += cen[3 + c] * wf0[(7 + c) * 18 + j];
#pragma unroll
            for (int c = 0; c < 3; ++c) bs -= cen[c] * sw0[c * 18 + j];
#pragma unroll
            for (int c = 0; c < 4; ++c) bs += cen[3 + c] * sw0[(3 + c) * 18 + j];
            wsp[OFF_AF + i * 20 + j] = af * TANH_K;
            wsp[OFF_AS + i * 20 + j] = as * TANH_K;
            wsp[OFF_BF + i * 20 + j] = bf * TANH_K;
            wsp[OFF_BS + i * 20 + j] = bs * TANH_K;
        }
        wsp[OFF_AF + i * 20 + 18] = 0.f; wsp[OFF_AF + i * 20 + 19] = 0.f;
        wsp[OFF_AS + i * 20 + 18] = 0.f; wsp[OFF_AS + i * 20 + 19] = 0.f;
        wsp[OFF_BF + i * 20 + 18] = 0.f; wsp[OFF_BF + i * 20 + 19] = 0.f;
        wsp[OFF_BS + i * 20 + 18] = 0.f; wsp[OFF_BS + i * 20 + 19] = 0.f;
        // bit-packed flag masks: one u64 per 64-aligned m-group
        const unsigned long long bal_f = __ballot(d[6] > 0.f);
        const unsigned long long bal_s = __ballot(d[6] < 1.f);
        if ((i & 63) == 0) {
            ((unsigned long long*)(wsp + OFF_FB))[i >> 6] = bal_f;
            ((unsigned long long*)(wsp + OFF_SB))[i >> 6] = bal_s;
        }
    }
    if (blockIdx.x == 0) {
        int t = threadIdx.x;
        float* wp = wsp + OFF_WP;
        for (int k = t; k < 162; k += 256) wp[WP_W1 + k] = wf1[k] * TANH_K;
        for (int k = t; k < 9;   k += 256) wp[WP_B1 + k] = bf1[k] * TANH_K;
        for (int k = t; k < 54;  k += 256) wp[WP_W2 + k] = wf2[k] * TANH_K;
        for (int k = t; k < 6;   k += 256) wp[WP_B2 + k] = bf2[k] * TANH_K;
        for (int k = t; k < 18;  k += 256) wp[WP_W3 + k] = wf3[k];
        for (int k = t; k < 3;   k += 256) wp[WP_B3 + k] = bf3[k];
        for (int k = t; k < 162; k += 256) wp[WP_SOLID + WP_W1 + k] = sw1[k] * TANH_K;
        for (int k = t; k < 9;   k += 256) wp[WP_SOLID + WP_B1 + k] = sb1[k] * TANH_K;
        for (int k = t; k < 54;  k += 256) wp[WP_SOLID + WP_W2 + k] = sw2[k] * TANH_K;
        for (int k = t; k < 6;   k += 256) wp[WP_SOLID + WP_B2 + k] = sb2[k] * TANH_K;
        for (int k = t; k < 18;  k += 256) wp[WP_SOLID + WP_W3 + k] = sw3[k];
        for (int k = t; k < 3;   k += 256) wp[WP_SOLID + WP_B3 + k] = sb3[k];
    }
}

// Fused: in-block mask compaction (deterministic per-wave segments ->
// prefix -> flat LDS lists, ascending-m order == old global list order)
// followed by the champion eval loops.
__global__ __launch_bounds__(256, 4)
void main_fused(const int* __restrict__ mask,
                const float* __restrict__ wsp,
                float* __restrict__ out) {
    __shared__ unsigned short segF[2048], segS[2048];
    __shared__ unsigned short flatF[2048], flatS[2048];
    __shared__ int wc[8];   // [0..3]=fluid per-wave counts, [4..7]=solid
    __shared__ int pc[10];  // [0..4]=fluid prefix, [5..9]=solid prefix
    __shared__ float red[3][4];
    const int n = blockIdx.x;
    const int tid = threadIdx.x;
    const int w = tid >> 6, lane = tid & 63;
    const int* mrow = mask + (size_t)n * MCOLS;
    const unsigned long long* fb = (const unsigned long long*)(wsp + OFF_FB);
    const unsigned long long* sbits = (const unsigned long long*)(wsp + OFF_SB);
    const unsigned long long ltm = (1ull << lane) - 1ull;

    // phase 1: per-wave segment compaction over m in [w*512, w*512+512)
    int cf = 0, cs = 0;
#pragma unroll 1
    for (int it = 0; it < 8; ++it) {
        const int m = w * 512 + it * 64 + lane;
        const int widx = w * 8 + it;               // wave-uniform word index
        const int mk = mrow[m];
        const bool af = mk && ((fb[widx] >> lane) & 1ull);
        const bool as = mk && ((sbits[widx] >> lane) & 1ull);
        const unsigned long long bf_ = __ballot(af);
        const unsigned long long bs_ = __ballot(as);
        if (af) segF[w * 512 + cf + __popcll(bf_ & ltm)] = (unsigned short)m;
        if (as) segS[w * 512 + cs + __popcll(bs_ & ltm)] = (unsigned short)m;
        cf += __popcll(bf_);
        cs += __popcll(bs_);
    }
    if (lane == 0) { wc[w] = cf; wc[4 + w] = cs; }
    __syncthreads();
    if (tid == 0) {
        int aF = 0, aS = 0;
#pragma unroll
        for (int k = 0; k < 4; ++k) {
            pc[k] = aF; aF += wc[k];
            pc[5 + k] = aS; aS += wc[4 + k];
        }
        pc[4] = aF; pc[9] = aS;
    }
    __syncthreads();
    // phase 2: copy own segment to flat position (keeps ascending-m order)
    {
        const int baseF = pc[w], cntF = wc[w];
        for (int k = lane; k < cntF; k += 64) flatF[baseF + k] = segF[w * 512 + k];
        const int baseS = pc[5 + w], cntS = wc[4 + w];
        for (int k = lane; k < cntS; k += 64) flatS[baseS + k] = segS[w * 512 + k];
    }
    __syncthreads();
    const int cftot = pc[4], cstot = pc[9];

    // phase 3: champion eval
    const float* __restrict__ W  = wsp + OFF_WP;
    const float* __restrict__ Bf = wsp + OFF_BF + n * 20;
    const float* __restrict__ Bs = wsp + OFF_BS + n * 20;
    float p0 = 0.f, p1 = 0.f, p2 = 0.f;
    row_loop_ilp(wsp + OFF_AF, flatF, cftot, Bf, W, tid, p0, p1, p2);
    row_loop_ilp(wsp + OFF_AS, flatS, cstot, Bs, W + WP_SOLID, tid, p0, p1, p2);

#pragma unroll
    for (int off = 32; off > 0; off >>= 1) {
        p0 += __shfl_xor(p0, off, 64);
        p1 += __shfl_xor(p1, off, 64);
        p2 += __shfl_xor(p2, off, 64);
    }
    if (lane == 0) { red[0][w] = p0; red[1][w] = p1; red[2][w] = p2; }
    __syncthreads();
    if (tid == 0) {
        float a0 = 0.f, a1 = 0.f, a2 = 0.f;
#pragma unroll
        for (int k = 0; k < 4; ++k) { a0 += red[0][k]; a1 += red[1][k]; a2 += red[2][k]; }
        out[n * 3 + 0] = a0; out[n * 3 + 1] = a1; out[n * 3 + 2] = a2;
    }
}

extern "C" void kernel_launch(void* const* d_in, const int* in_sizes, int n_in,
                              void* d_out, int out_size, void* d_ws, size_t ws_size,
                              hipStream_t stream) {
    const int*   mask  = (const int*)d_in[0];
    const int*   index = (const int*)d_in[1];
    const float* data  = (const float*)d_in[2];
    const float* wf0   = (const float*)d_in[3];
    const float* bf0   = (const float*)d_in[4];
    const float* wf1   = (const float*)d_in[5];
    const float* bf1   = (const float*)d_in[6];
    const float* wf2   = (const float*)d_in[7];
    const float* bf2   = (const float*)d_in[8];
    const float* wf3   = (const float*)d_in[9];
    const float* bf3   = (const float*)d_in[10];
    const float* sw0   = (const float*)d_in[11];
    const float* sb0   = (const float*)d_in[12];
    const float* sw1   = (const float*)d_in[13];
    const float* sb1   = (const float*)d_in[14];
    const float* sw2   = (const float*)d_in[15];
    const float* sb2   = (const float*)d_in[16];
    const float* sw3   = (const float*)d_in[17];
    const float* sb3   = (const float*)d_in[18];
    float* wsp = (float*)d_ws;
    float* out = (float*)d_out;

    prep_kernel<<<dim3(8), dim3(256), 0, stream>>>(
        index, data, wf0, bf0, sw0, sb0, wf1, bf1, wf2, bf2, wf3, bf3,
        sw1, sb1, sw2, sb2, sw3, sb3, wsp);
    main_fused<<<dim3(NROWS), dim3(256), 0, stream>>>(mask, wsp, out);
}

// Round 19
// 59.148 us; speedup vs baseline: 2.0246x; 1.0187x over previous
//
#include <hip/hip_runtime.h>

#define NROWS 2048
#define MCOLS 2048

// ---- d_ws layout (float offsets); rows padded to stride 20 ----
#define OFF_AF 0
#define OFF_AS (OFF_AF + NROWS * 20)
#define OFF_BF (OFF_AS + NROWS * 20)
#define OFF_BS (OFF_BF + NROWS * 20)
#define OFF_WP (OFF_BS + NROWS * 20)
#define OFF_FB (OFF_WP + 512)   // u64[32]: fluid bit per m (flag>0)
#define OFF_SB (OFF_FB + 64)    // u64[32]: solid bit per m (flag<1)

#define WP_W1 0
#define WP_B1 162
#define WP_W2 171
#define WP_B2 225
#define WP_W3 231
#define WP_B3 249
#define WP_SOLID 252

// 2*log2(e): folded into A/B rows and W1/b1/W2/b2 at prep (R14, +12%).
#define TANH_K 2.8853900817779268f

// tanh with the scale pre-folded: tanh(x) = 1 - 2/(1 + 2^(K x)).
__device__ __forceinline__ float tanh_pre(float x) {
    float t = __builtin_amdgcn_exp2f(x);
    return 1.0f - 2.0f * __builtin_amdgcn_rcpf(1.0f + t);
}

// Champion eval (R11 + R14): scalar math + layer-ILP asm fences.
// Fences force all 18/9/6 activations simultaneously live so the compiler
// cannot re-serialize the independent tanh chains (hidden 1.7x cost through
// R10). Weight/bias reads are block-uniform -> s_load. Closed levers
// (measured, do not revisit): occupancy>4 (R7/R14), pk-packing (R8/R12),
// dual-eval ILP (R15), LDS tiling (R10), trans-reduction (R16).
__device__ __forceinline__ void eval_regs_ilp(float4 P0, float4 P1, float4 P2,
                                              float4 P3, float2 P4,
                                              const float* __restrict__ Bq,
                                              const float* __restrict__ W,
                                              float& p0, float& p1, float& p2) {
    float h[18];
    h[0]  = tanh_pre(P0.x + Bq[0]);  h[1]  = tanh_pre(P0.y + Bq[1]);
    h[2]  = tanh_pre(P0.z + Bq[2]);  h[3]  = tanh_pre(P0.w + Bq[3]);
    h[4]  = tanh_pre(P1.x + Bq[4]);  h[5]  = tanh_pre(P1.y + Bq[5]);
    h[6]  = tanh_pre(P1.z + Bq[6]);  h[7]  = tanh_pre(P1.w + Bq[7]);
    h[8]  = tanh_pre(P2.x + Bq[8]);  h[9]  = tanh_pre(P2.y + Bq[9]);
    h[10] = tanh_pre(P2.z + Bq[10]); h[11] = tanh_pre(P2.w + Bq[11]);
    h[12] = tanh_pre(P3.x + Bq[12]); h[13] = tanh_pre(P3.y + Bq[13]);
    h[14] = tanh_pre(P3.z + Bq[14]); h[15] = tanh_pre(P3.w + Bq[15]);
    h[16] = tanh_pre(P4.x + Bq[16]); h[17] = tanh_pre(P4.y + Bq[17]);
    asm volatile("" : "+v"(h[0]), "+v"(h[1]), "+v"(h[2]), "+v"(h[3]),
                      "+v"(h[4]), "+v"(h[5]), "+v"(h[6]), "+v"(h[7]),
                      "+v"(h[8]), "+v"(h[9]), "+v"(h[10]), "+v"(h[11]),
                      "+v"(h[12]), "+v"(h[13]), "+v"(h[14]), "+v"(h[15]),
                      "+v"(h[16]), "+v"(h[17]));
    float g[9];
#pragma unroll
    for (int o = 0; o < 9; ++o) g[o] = W[WP_B1 + o];
#pragma unroll
    for (int j = 0; j < 18; ++j) {
        const float a = h[j];
#pragma unroll
        for (int o = 0; o < 9; ++o) g[o] += a * W[WP_W1 + j * 9 + o];
    }
#pragma unroll
    for (int o = 0; o < 9; ++o) g[o] = tanh_pre(g[o]);
    asm volatile("" : "+v"(g[0]), "+v"(g[1]), "+v"(g[2]), "+v"(g[3]),
                      "+v"(g[4]), "+v"(g[5]), "+v"(g[6]), "+v"(g[7]),
                      "+v"(g[8]));
    float q[6];
#pragma unroll
    for (int o = 0; o < 6; ++o) q[o] = W[WP_B2 + o];
#pragma unroll
    for (int j = 0; j < 9; ++j) {
        const float a = g[j];
#pragma unroll
        for (int o = 0; o < 6; ++o) q[o] += a * W[WP_W2 + j * 6 + o];
    }
#pragma unroll
    for (int o = 0; o < 6; ++o) q[o] = tanh_pre(q[o]);
    asm volatile("" : "+v"(q[0]), "+v"(q[1]), "+v"(q[2]), "+v"(q[3]),
                      "+v"(q[4]), "+v"(q[5]));
    float o0 = W[WP_B3 + 0], o1 = W[WP_B3 + 1], o2 = W[WP_B3 + 2];
#pragma unroll
    for (int j = 0; j < 6; ++j) {
        const float a = q[j];
        o0 += a * W[WP_W3 + j * 3 + 0];
        o1 += a * W[WP_W3 + j * 3 + 1];
        o2 += a * W[WP_W3 + j * 3 + 2];
    }
    p0 += o0; p1 += o1; p2 += o2;
}

// champion loop: scalar ILP eval + 2-deep register prefetch of next A-row.
__device__ __forceinline__ void row_loop_ilp(const float* __restrict__ A,
                                             const unsigned short* lst,
                                             int cnt,
                                             const float* __restrict__ Bq,
                                             const float* __restrict__ W,
                                             int tid,
                                             float& p0, float& p1, float& p2) {
    int i = tid;
    if (i >= cnt) return;
    const float* r = A + (int)lst[i] * 20;
    float4 P0 = *(const float4*)(r);
    float4 P1 = *(const float4*)(r + 4);
    float4 P2 = *(const float4*)(r + 8);
    float4 P3 = *(const float4*)(r + 12);
    float2 P4 = *(const float2*)(r + 16);
    for (;;) {
        const int inext = i + 256;
        const bool more = inext < cnt;
        const float* rn = A + (int)lst[more ? inext : i] * 20;
        const float4 N0 = *(const float4*)(rn);
        const float4 N1 = *(const float4*)(rn + 4);
        const float4 N2 = *(const float4*)(rn + 8);
        const float4 N3 = *(const float4*)(rn + 12);
        const float2 N4 = *(const float2*)(rn + 16);
        eval_regs_ilp(P0, P1, P2, P3, P4, Bq, W, p0, p1, p2);
        if (!more) break;
        P0 = N0; P1 = N1; P2 = N2; P3 = N3; P4 = N4;
        i = inext;
    }
}

__global__ void prep_kernel(const int* __restrict__ index,
                            const float* __restrict__ data,
                            const float* __restrict__ wf0, const float* __restrict__ bf0,
                            const float* __restrict__ sw0, const float* __restrict__ sb0,
                            const float* __restrict__ wf1, const float* __restrict__ bf1,
                            const float* __restrict__ wf2, const float* __restrict__ bf2,
                            const float* __restrict__ wf3, const float* __restrict__ bf3,
                            const float* __restrict__ sw1, const float* __restrict__ sb1,
                            const float* __restrict__ sw2, const float* __restrict__ sb2,
                            const float* __restrict__ sw3, const float* __restrict__ sb3,
                            float* __restrict__ wsp) {
    int i = blockIdx.x * blockDim.x + threadIdx.x;
    if (i < NROWS) {
        float d[7], cen[7];
#pragma unroll
        for (int c = 0; c < 7; ++c) d[c] = data[i * 7 + c];
        int ci = index[i];
#pragma unroll
        for (int c = 0; c < 7; ++c) cen[c] = data[ci * 7 + c];
#pragma unroll
        for (int j = 0; j < 18; ++j) {
            float af = 0.f;
#pragma unroll
            for (int c = 0; c < 7; ++c) af += d[c] * wf0[c * 18 + j];
            float as = d[0] * sw0[0 * 18 + j] + d[1] * sw0[1 * 18 + j] + d[2] * sw0[2 * 18 + j];
            float bf = bf0[j], bs = sb0[j];
#pragma unroll
            for (int c = 0; c < 3; ++c) bf -= cen[c] * wf0[c * 18 + j];
#pragma unroll
            for (int c = 0; c < 4; ++c) bf += cen[3 + c] * wf0[(7 + c) * 18 + j];
#pragma unroll
            for (int c = 0; c < 3; ++c) bs -= cen[c] * sw0[c * 18 + j];
#pragma unroll
            for (int c = 0; c < 4; ++c) bs += cen[3 + c] * sw0[(3 + c) * 18 + j];
            wsp[OFF_AF + i * 20 + j] = af * TANH_K;
            wsp[OFF_AS + i * 20 + j] = as * TANH_K;
            wsp[OFF_BF + i * 20 + j] = bf * TANH_K;
            wsp[OFF_BS + i * 20 + j] = bs * TANH_K;
        }
        wsp[OFF_AF + i * 20 + 18] = 0.f; wsp[OFF_AF + i * 20 + 19] = 0.f;
        wsp[OFF_AS + i * 20 + 18] = 0.f; wsp[OFF_AS + i * 20 + 19] = 0.f;
        wsp[OFF_BF + i * 20 + 18] = 0.f; wsp[OFF_BF + i * 20 + 19] = 0.f;
        wsp[OFF_BS + i * 20 + 18] = 0.f; wsp[OFF_BS + i * 20 + 19] = 0.f;
        const unsigned long long bal_f = __ballot(d[6] > 0.f);
        const unsigned long long bal_s = __ballot(d[6] < 1.f);
        if ((i & 63) == 0) {
            ((unsigned long long*)(wsp + OFF_FB))[i >> 6] = bal_f;
            ((unsigned long long*)(wsp + OFF_SB))[i >> 6] = bal_s;
        }
    }
    if (blockIdx.x == 0) {
        int t = threadIdx.x;
        float* wp = wsp + OFF_WP;
        for (int k = t; k < 162; k += 256) wp[WP_W1 + k] = wf1[k] * TANH_K;
        for (int k = t; k < 9;   k += 256) wp[WP_B1 + k] = bf1[k] * TANH_K;
        for (int k = t; k < 54;  k += 256) wp[WP_W2 + k] = wf2[k] * TANH_K;
        for (int k = t; k < 6;   k += 256) wp[WP_B2 + k] = bf2[k] * TANH_K;
        for (int k = t; k < 18;  k += 256) wp[WP_W3 + k] = wf3[k];
        for (int k = t; k < 3;   k += 256) wp[WP_B3 + k] = bf3[k];
        for (int k = t; k < 162; k += 256) wp[WP_SOLID + WP_W1 + k] = sw1[k] * TANH_K;
        for (int k = t; k < 9;   k += 256) wp[WP_SOLID + WP_B1 + k] = sb1[k] * TANH_K;
        for (int k = t; k < 54;  k += 256) wp[WP_SOLID + WP_W2 + k] = sw2[k] * TANH_K;
        for (int k = t; k < 6;   k += 256) wp[WP_SOLID + WP_B2 + k] = sb2[k] * TANH_K;
        for (int k = t; k < 18;  k += 256) wp[WP_SOLID + WP_W3 + k] = sw3[k];
        for (int k = t; k < 3;   k += 256) wp[WP_SOLID + WP_B3 + k] = sb3[k];
    }
}

// Fused main: batched mask loads (8 outstanding, one wait) -> per-wave
// segment compaction -> prefix -> flat LDS lists -> champion eval.
__global__ __launch_bounds__(256, 4)
void main_fused(const int* __restrict__ mask,
                const float* __restrict__ wsp,
                float* __restrict__ out) {
    __shared__ unsigned short segF[2048], segS[2048];
    __shared__ unsigned short flatF[2048], flatS[2048];
    __shared__ int wc[8];
    __shared__ int pc[10];
    __shared__ float red[3][4];
    const int n = blockIdx.x;
    const int tid = threadIdx.x;
    const int w = tid >> 6, lane = tid & 63;
    const int* mrow = mask + (size_t)n * MCOLS;
    const unsigned long long* fb = (const unsigned long long*)(wsp + OFF_FB);
    const unsigned long long* sbits = (const unsigned long long*)(wsp + OFF_SB);
    const unsigned long long ltm = (1ull << lane) - 1ull;

    // phase 1a: issue ALL 8 mask loads back-to-back (8 outstanding vmcnt)
    int mk[8];
#pragma unroll
    for (int it = 0; it < 8; ++it) mk[it] = mrow[w * 512 + it * 64 + lane];
    // phase 1b: ballot-compact from registers (no load latency in the chain)
    int cf = 0, cs = 0;
#pragma unroll
    for (int it = 0; it < 8; ++it) {
        const int m = w * 512 + it * 64 + lane;
        const int widx = w * 8 + it;
        const bool af = mk[it] && ((fb[widx] >> lane) & 1ull);
        const bool as = mk[it] && ((sbits[widx] >> lane) & 1ull);
        const unsigned long long bf_ = __ballot(af);
        const unsigned long long bs_ = __ballot(as);
        if (af) segF[w * 512 + cf + __popcll(bf_ & ltm)] = (unsigned short)m;
        if (as) segS[w * 512 + cs + __popcll(bs_ & ltm)] = (unsigned short)m;
        cf += __popcll(bf_);
        cs += __popcll(bs_);
    }
    if (lane == 0) { wc[w] = cf; wc[4 + w] = cs; }
    __syncthreads();
    if (tid == 0) {
        int aF = 0, aS = 0;
#pragma unroll
        for (int k = 0; k < 4; ++k) {
            pc[k] = aF; aF += wc[k];
            pc[5 + k] = aS; aS += wc[4 + k];
        }
        pc[4] = aF; pc[9] = aS;
    }
    __syncthreads();
    // phase 2: copy own segment to flat position (ascending-m order preserved)
    {
        const int baseF = pc[w], cntF = wc[w];
        for (int k = lane; k < cntF; k += 64) flatF[baseF + k] = segF[w * 512 + k];
        const int baseS = pc[5 + w], cntS = wc[4 + w];
        for (int k = lane; k < cntS; k += 64) flatS[baseS + k] = segS[w * 512 + k];
    }
    __syncthreads();
    const int cftot = pc[4], cstot = pc[9];

    // phase 3: champion eval
    const float* __restrict__ W  = wsp + OFF_WP;
    const float* __restrict__ Bf = wsp + OFF_BF + n * 20;
    const float* __restrict__ Bs = wsp + OFF_BS + n * 20;
    float p0 = 0.f, p1 = 0.f, p2 = 0.f;
    row_loop_ilp(wsp + OFF_AF, flatF, cftot, Bf, W, tid, p0, p1, p2);
    row_loop_ilp(wsp + OFF_AS, flatS, cstot, Bs, W + WP_SOLID, tid, p0, p1, p2);

#pragma unroll
    for (int off = 32; off > 0; off >>= 1) {
        p0 += __shfl_xor(p0, off, 64);
        p1 += __shfl_xor(p1, off, 64);
        p2 += __shfl_xor(p2, off, 64);
    }
    if (lane == 0) { red[0][w] = p0; red[1][w] = p1; red[2][w] = p2; }
    __syncthreads();
    if (tid == 0) {
        float a0 = 0.f, a1 = 0.f, a2 = 0.f;
#pragma unroll
        for (int k = 0; k < 4; ++k) { a0 += red[0][k]; a1 += red[1][k]; a2 += red[2][k]; }
        out[n * 3 + 0] = a0; out[n * 3 + 1] = a1; out[n * 3 + 2] = a2;
    }
}

extern "C" void kernel_launch(void* const* d_in, const int* in_sizes, int n_in,
                              void* d_out, int out_size, void* d_ws, size_t ws_size,
                              hipStream_t stream) {
    const int*   mask  = (const int*)d_in[0];
    const int*   index = (const int*)d_in[1];
    const float* data  = (const float*)d_in[2];
    const float* wf0   = (const float*)d_in[3];
    const float* bf0   = (const float*)d_in[4];
    const float* wf1   = (const float*)d_in[5];
    const float* bf1   = (const float*)d_in[6];
    const float* wf2   = (const float*)d_in[7];
    const float* bf2   = (const float*)d_in[8];
    const float* wf3   = (const float*)d_in[9];
    const float* bf3   = (const float*)d_in[10];
    const float* sw0   = (const float*)d_in[11];
    const float* sb0   = (const float*)d_in[12];
    const float* sw1   = (const float*)d_in[13];
    const float* sb1   = (const float*)d_in[14];
    const float* sw2   = (const float*)d_in[15];
    const float* sb2   = (const float*)d_in[16];
    const float* sw3   = (const float*)d_in[17];
    const float* sb3   = (const float*)d_in[18];
    float* wsp = (float*)d_ws;
    float* out = (float*)d_out;

    prep_kernel<<<dim3(8), dim3(256), 0, stream>>>(
        index, data, wf0, bf0, sw0, sb0, wf1, bf1, wf2, bf2, wf3, bf3,
        sw1, sb1, sw2, sb2, sw3, sb3, wsp);
    main_fused<<<dim3(NROWS), dim3(256), 0, stream>>>(mask, wsp, out);
}